// Round 2
// baseline (302.549 us; speedup 1.0000x reference)
//
#include <hip/hip_runtime.h>
#include <stdint.h>

#define T_ 256
#define B_ 8
#define E_ 512
#define H_ 32
#define HD_ 16
#define EXP_ 512
#define S_ 768          // T_ + EXP_
#define M_ 2048         // T_ * B_
#define SMOOTH_ 20.0f

// ---------------------------------------------------------------------------
// GEMM core: C[m][n] = sum_e X[m][e] * W[n][e]  (X: M_ x E_, W: E_ x E_ both
// row-major with e contiguous). 64x64 output tile, BK=16, 256 threads, 4x4
// per thread. LDS stored transposed (Xs[k][m]) so compute reads are float4:
// a-reads broadcast across tx (free), b-reads are 2-way wrap (free, m136).
// ---------------------------------------------------------------------------

__device__ __forceinline__ void gemm_body(const float* __restrict__ X,
                                          const float* __restrict__ W,
                                          int m0, int n0,
                                          float acc[4][4],
                                          float* Xs, float* Ws)
{
    const int tid = threadIdx.x;
    const int lr  = tid >> 2;        // 0..63 (tile row to load)
    const int lc4 = tid & 3;         // float4 column 0..3
    const int tx  = tid & 15;
    const int ty  = tid >> 4;

    for (int k0 = 0; k0 < E_; k0 += 16) {
        float4 xv = *(const float4*)&X[(size_t)(m0 + lr) * E_ + k0 + lc4 * 4];
        float4 wv = *(const float4*)&W[(size_t)(n0 + lr) * E_ + k0 + lc4 * 4];
        __syncthreads();
        Xs[(lc4 * 4 + 0) * 64 + lr] = xv.x;
        Xs[(lc4 * 4 + 1) * 64 + lr] = xv.y;
        Xs[(lc4 * 4 + 2) * 64 + lr] = xv.z;
        Xs[(lc4 * 4 + 3) * 64 + lr] = xv.w;
        Ws[(lc4 * 4 + 0) * 64 + lr] = wv.x;
        Ws[(lc4 * 4 + 1) * 64 + lr] = wv.y;
        Ws[(lc4 * 4 + 2) * 64 + lr] = wv.z;
        Ws[(lc4 * 4 + 3) * 64 + lr] = wv.w;
        __syncthreads();
#pragma unroll
        for (int kk = 0; kk < 16; ++kk) {
            float4 a4 = *(const float4*)&Xs[kk * 64 + ty * 4];
            float4 b4 = *(const float4*)&Ws[kk * 64 + tx * 4];
            float a[4] = {a4.x, a4.y, a4.z, a4.w};
            float b[4] = {b4.x, b4.y, b4.z, b4.w};
#pragma unroll
            for (int i = 0; i < 4; ++i)
#pragma unroll
                for (int j = 0; j < 4; ++j)
                    acc[i][j] += a[i] * b[j];
        }
    }
}

__global__ __launch_bounds__(256)
void qkv_gemm(const float* __restrict__ X,
              const float* __restrict__ Wq, const float* __restrict__ bq,
              const float* __restrict__ Wk,
              const float* __restrict__ Wv, const float* __restrict__ bv,
              float* __restrict__ Q, float* __restrict__ K, float* __restrict__ V)
{
    __shared__ float Xs[16 * 64];
    __shared__ float Ws[16 * 64];
    const int z = blockIdx.z;
    const float* W    = (z == 0) ? Wq : (z == 1 ? Wk : Wv);
    const float* bias = (z == 0) ? bq : (z == 1 ? nullptr : bv);
    float* dst        = (z == 0) ? Q  : (z == 1 ? K  : V);
    const int rows    = (z == 0) ? T_ : S_;

    const int m0 = blockIdx.y * 64;
    const int n0 = blockIdx.x * 64;
    float acc[4][4] = {};
    gemm_body(X, W, m0, n0, acc, Xs, Ws);

    const int tx = threadIdx.x & 15;
    const int ty = threadIdx.x >> 4;
    float4 bias4 = make_float4(0.f, 0.f, 0.f, 0.f);
    if (bias) bias4 = *(const float4*)&bias[n0 + tx * 4];
#pragma unroll
    for (int i = 0; i < 4; ++i) {
        const int m = m0 + ty * 4 + i;
        const int t = m >> 3;          // m / B_
        const int b = m & 7;           // m % B_
        const int n = n0 + tx * 4;     // 4 consecutive cols, within one head
        const int h = n >> 4;
        const int d = n & 15;
        float4 o;
        o.x = acc[i][0] + bias4.x;
        o.y = acc[i][1] + bias4.y;
        o.z = acc[i][2] + bias4.z;
        o.w = acc[i][3] + bias4.w;
        *(float4*)&dst[(((size_t)(b * H_ + h)) * rows + t) * HD_ + d] = o;
    }
}

__global__ __launch_bounds__(256)
void out_gemm(const float* __restrict__ X, const float* __restrict__ Wo,
              const float* __restrict__ bo, float* __restrict__ dst)
{
    __shared__ float Xs[16 * 64];
    __shared__ float Ws[16 * 64];
    const int m0 = blockIdx.y * 64;
    const int n0 = blockIdx.x * 64;
    float acc[4][4] = {};
    gemm_body(X, Wo, m0, n0, acc, Xs, Ws);

    const int tx = threadIdx.x & 15;
    const int ty = threadIdx.x >> 4;
    float4 bias4 = *(const float4*)&bo[n0 + tx * 4];
#pragma unroll
    for (int i = 0; i < 4; ++i) {
        const int m = m0 + ty * 4 + i;
        float4 o;
        o.x = acc[i][0] + bias4.x;
        o.y = acc[i][1] + bias4.y;
        o.z = acc[i][2] + bias4.z;
        o.w = acc[i][3] + bias4.w;
        *(float4*)&dst[(size_t)m * E_ + n0 + tx * 4] = o;
    }
}

// ---------------------------------------------------------------------------
// K/V expansion: rows [T_, S_) of K,V are gathers of rows [0, T_).
// One block per (b, j); threads 0..127 copy K (32 heads x 4 float4),
// threads 128..255 copy V.
// ---------------------------------------------------------------------------
__global__ __launch_bounds__(256)
void gather_kernel(const int* __restrict__ oc,
                   float* __restrict__ Kb, float* __restrict__ Vb)
{
    const int bj  = blockIdx.x;      // b * EXP_ + j
    const int b   = bj >> 9;
    const int j   = bj & 511;
    const int src = oc[bj];          // in [0, T_)

    const int tid   = threadIdx.x;
    const int which = tid >> 7;
    const int i     = tid & 127;     // h = i>>2, f4 = i&3
    const int h     = i >> 2;
    const int f4    = i & 3;
    float* P = which ? Vb : Kb;
    const float4* s4 = (const float4*)&P[(((size_t)(b * H_ + h)) * S_ + src) * HD_];
    float4*       d4 = (float4*)&P[(((size_t)(b * H_ + h)) * S_ + T_ + j) * HD_];
    d4[f4] = s4[f4];
}

// ---------------------------------------------------------------------------
// Attention: one block per (b,h), 256 threads = one t-row each.
// K/V staged in LDS in 256-row tiles; all lanes read the same K[s]/V[s]
// (LDS broadcast). Softmax uses a fixed reference point (50.0f): x is
// bounded in ~[-30,30] so exp(x-50) never overflows and the scale cancels
// in acc/Z -- no online-max rescaling needed.
// Masks are int32 on device (harness uploads bool as int).
// ---------------------------------------------------------------------------
__global__ __launch_bounds__(256)
void attn_kernel(const float* __restrict__ Q, const float* __restrict__ Kb,
                 const float* __restrict__ Vb, const float* __restrict__ LAW,
                 const int* __restrict__ kpm, const int* __restrict__ em,
                 float* __restrict__ A)
{
    __shared__ float Ks[256 * 16];
    __shared__ float Vs[256 * 16];
    __shared__ int ms[256];

    const int bh = blockIdx.x;
    const int b  = bh >> 5;
    const int t  = threadIdx.x;

    float q[16];
    {
        const float4* qp = (const float4*)&Q[((size_t)bh * T_ + t) * HD_];
#pragma unroll
        for (int i = 0; i < 4; ++i) {
            float4 v = qp[i];
            q[4 * i + 0] = v.x; q[4 * i + 1] = v.y;
            q[4 * i + 2] = v.z; q[4 * i + 3] = v.w;
        }
    }

    float Z = 0.f;
    float acc[16] = {};
    const float* lawp = &LAW[((size_t)b * T_ + t) * S_];

    for (int s0 = 0; s0 < S_; s0 += 256) {
        __syncthreads();
        {
            const float4* Kg = (const float4*)&Kb[((size_t)bh * S_ + s0) * HD_];
            const float4* Vg = (const float4*)&Vb[((size_t)bh * S_ + s0) * HD_];
            float4* Ks4 = (float4*)Ks;
            float4* Vs4 = (float4*)Vs;
#pragma unroll
            for (int i = 0; i < 4; ++i) {
                Ks4[t + 256 * i] = Kg[t + 256 * i];
                Vs4[t + 256 * i] = Vg[t + 256 * i];
            }
            const int s = s0 + t;
            ms[t] = (s < T_) ? kpm[b * T_ + s] : em[b * EXP_ + (s - T_)];
        }
        __syncthreads();

        for (int ss = 0; ss < 256; ss += 4) {
            float4 lw = *(const float4*)&lawp[s0 + ss];
            float lwa[4] = {lw.x, lw.y, lw.z, lw.w};
#pragma unroll
            for (int u = 0; u < 4; ++u) {
                const float4* kr = (const float4*)&Ks[(ss + u) * 16];
                float sc = 0.f;
#pragma unroll
                for (int i = 0; i < 4; ++i) {
                    float4 kv = kr[i];
                    sc += q[4 * i + 0] * kv.x + q[4 * i + 1] * kv.y
                        + q[4 * i + 2] * kv.z + q[4 * i + 3] * kv.w;
                }
                const float x = (sc + SMOOTH_) * lwa[u] - SMOOTH_;
                const float e = ms[ss + u] ? 0.f : __expf(x - 50.f);
                Z += e;
                const float w = e * lwa[u];
                const float4* vr = (const float4*)&Vs[(ss + u) * 16];
#pragma unroll
                for (int i = 0; i < 4; ++i) {
                    float4 vv = vr[i];
                    acc[4 * i + 0] += w * vv.x;
                    acc[4 * i + 1] += w * vv.y;
                    acc[4 * i + 2] += w * vv.z;
                    acc[4 * i + 3] += w * vv.w;
                }
            }
        }
    }

    const float inv = (Z > 0.f) ? 1.f / Z : 0.f;
    float4* op = (float4*)&A[(((size_t)t * B_) + b) * E_ + (bh & 31) * HD_];
#pragma unroll
    for (int i = 0; i < 4; ++i) {
        float4 o;
        o.x = acc[4 * i + 0] * inv; o.y = acc[4 * i + 1] * inv;
        o.z = acc[4 * i + 2] * inv; o.w = acc[4 * i + 3] * inv;
        op[i] = o;
    }
}

// ---------------------------------------------------------------------------
extern "C" void kernel_launch(void* const* d_in, const int* in_sizes, int n_in,
                              void* d_out, int out_size, void* d_ws, size_t ws_size,
                              hipStream_t stream)
{
    const float* query = (const float*)d_in[0];
    const int*   oc    = (const int*)d_in[1];
    const int*   em    = (const int*)d_in[2];   // bool uploaded as int32
    const int*   kpm   = (const int*)d_in[3];   // bool uploaded as int32
    const float* law   = (const float*)d_in[4];
    const float* Wq    = (const float*)d_in[5];
    const float* bq    = (const float*)d_in[6];
    const float* Wk    = (const float*)d_in[7];
    const float* Wv    = (const float*)d_in[8];
    const float* bv    = (const float*)d_in[9];
    const float* Wo    = (const float*)d_in[10];
    const float* bo    = (const float*)d_in[11];
    float* out = (float*)d_out;

    float* ws = (float*)d_ws;
    float* Q = ws;                       // [B][H][T][16]   = 1,048,576 f
    float* K = Q + (size_t)1048576;      // [B][H][S][16]   = 3,145,728 f
    float* V = K + (size_t)3145728;      // [B][H][S][16]   = 3,145,728 f
    float* A = V + (size_t)3145728;      // [t][b][e]       = 1,048,576 f

    dim3 gq(E_ / 64, M_ / 64, 3);
    qkv_gemm<<<gq, 256, 0, stream>>>(query, Wq, bq, Wk, Wv, bv, Q, K, V);

    gather_kernel<<<B_ * EXP_, 256, 0, stream>>>(oc, K, V);

    attn_kernel<<<B_ * H_, 256, 0, stream>>>(Q, K, V, law, kpm, em, A);

    dim3 go(E_ / 64, M_ / 64, 1);
    out_gemm<<<go, 256, 0, stream>>>(A, Wo, bo, out);
}